// Round 15
// baseline (123.578 us; speedup 1.0000x reference)
//
#include <hip/hip_runtime.h>
#include <math.h>

// Problem constants (fixed by the reference: B=4, N=4096, D=3)
constexpr int B_  = 4;
constexpr int N_  = 4096;
constexpr int NV  = N_ * 3;      // 12288 flattened residual elements per (batch,dir)
constexpr int NCCH = 32;         // candidate chunks
constexpr int CCH  = N_ / NCCH;  // 128 candidates per chunk
constexpr int QPT  = 2;          // queries per thread in the NN kernel
constexpr int TPB_TAIL = 1024;   // tail kernel block size

// float <-> monotonic uint key (order-preserving bijection on finite floats)
__device__ inline unsigned f2k(float f) {
    unsigned b = __float_as_uint(f);
    return b ^ ((unsigned)((int)b >> 31) | 0x80000000u);
}
__device__ inline float k2f(unsigned k) {
    unsigned b = (k & 0x80000000u) ? (k ^ 0x80000000u) : ~k;
    return __uint_as_float(b);
}

// ---------------------------------------------------------------------------
// Kernel 0: prescale candidates: pre[t] = {-2bx,-2by,-2bz,|b|^2}.
// grid = (B_*N_/256, 2): y-dim picks x or y input.
// ---------------------------------------------------------------------------
__global__ __launch_bounds__(256) void prescale_kernel(const float* __restrict__ x,
                                                       const float* __restrict__ y,
                                                       float4* __restrict__ preX,
                                                       float4* __restrict__ preY) {
    const int t = blockIdx.x * 256 + threadIdx.x;        // 0 .. B_*N_-1
    const float* src = blockIdx.y == 0 ? x : y;
    float4* dst      = blockIdx.y == 0 ? preX : preY;
    float bx = src[t * 3 + 0];
    float by = src[t * 3 + 1];
    float bz = src[t * 3 + 2];
    dst[t] = make_float4(-2.f * bx, -2.f * by, -2.f * bz,
                         bx * bx + by * by + bz * bz);
}

// ---------------------------------------------------------------------------
// Kernel 1: partial NN, scalar candidate loads, QPT=2.
// grid = (NCCH=32, 4096/(256*2)=8 qchunks, 8 pairs) = 2048 blocks = 8/CU
//      = 8 waves/SIMD (TLP preserved — R10-12: TLP dominates here).
// QPT=2 amortizes PER-ITERATION overhead (loop bookkeeping, s_load issue,
// address inc) over 2 queries while per-pair work (3 FMA + cmp/cndmask/min)
// is unchanged. R14 measured t_nn=26.3us = ~15.4 insts/pair vs 6 designed;
// if the excess is per-iter this drops toward ~18us, if per-pair it won't
// move (-> next: LDS hybrid or grid pruning).
// Strict '<' keeps the FIRST minimal index (jnp.argmin tie-break).
// ---------------------------------------------------------------------------
__global__ __launch_bounds__(256) void nn_scalar_kernel(const float* __restrict__ x,
                                                        const float* __restrict__ y,
                                                        const float4* __restrict__ preX,
                                                        const float4* __restrict__ preY,
                                                        float4* __restrict__ part) {
    const int pair = blockIdx.z;
    const int b    = pair >> 1;
    const int dir  = pair & 1;              // 0: S1=x,S2=y ; 1: S1=y,S2=x
    const float*  S1 = (dir == 0 ? x : y) + b * NV;
    const float4* P2 = (dir == 0 ? preY : preX) + b * N_;
    const int cbase = blockIdx.x * CCH;

    // 2 contiguous queries: 6 floats = 3 aligned float2 loads (q0 even).
    const int q0 = blockIdx.y * 512 + threadIdx.x * QPT;
    const float2* p2 = (const float2*)(S1 + q0 * 3);
    const float2 v0 = p2[0], v1 = p2[1], v2 = p2[2];
    const float ax0 = v0.x, ay0 = v0.y, az0 = v1.x;
    const float ax1 = v1.y, ay1 = v2.x, az1 = v2.y;

    float bd0 = INFINITY, bd1 = INFINITY;
    int idx0 = 0, idx1 = 0;
    #pragma unroll 8
    for (int j = 0; j < CCH; ++j) {
        const float4 c = P2[cbase + j];     // wave-uniform -> scalar load
        const int jg = cbase + j;
        // d2 = |b|^2 - 2 a.b  (3 FMAs per query on prescaled candidate)
        float d20 = fmaf(ax0, c.x, fmaf(ay0, c.y, fmaf(az0, c.z, c.w)));
        float d21 = fmaf(ax1, c.x, fmaf(ay1, c.y, fmaf(az1, c.z, c.w)));
        if (d20 < bd0) idx0 = jg;           // v_cmp + v_cndmask
        bd0 = fminf(d20, bd0);              // v_min
        if (d21 < bd1) idx1 = jg;
        bd1 = fminf(d21, bd1);
    }

    // One 16B store for both queries' (d2, idx).
    part[((size_t)(pair * NCCH + blockIdx.x) * N_ + q0) >> 1] =
        make_float4(bd0, (float)idx0, bd1, (float)idx1);
}

// ---------------------------------------------------------------------------
// Kernel 2 (FUSED MERGE + TAIL): one block per (batch,dir) pair, 1024 thr.
//   A: merge NCCH partials per query INLINE (8-unrolled independent loads,
//      16 waves/CU hide L2 latency — unlike R8's serial-chain at 40 VGPR),
//      gather residuals, monotonic keys -> LDS. No global keys roundtrip.
//   B: 4x 8-bit MSD radix-select for all four quantile order-stats at once
//      (uint4-vectorized scans; pass-1 hist has 8 wave-group-private copies).
//   C: fused count(<=key0)/min(>key0) -> linear-interp quantiles
//      (positions in fp32, identical to jnp.quantile).
//   D: two-pass masked mean/std from LDS keys (k2f exact inverse).
// ---------------------------------------------------------------------------
__global__ __launch_bounds__(TPB_TAIL) void fused_tail_kernel(const float* __restrict__ x,
                                                              const float* __restrict__ y,
                                                              const float2* __restrict__ part,
                                                              float* __restrict__ stats) {
    __shared__ unsigned keys[NV];           // 48 KB
    __shared__ int hist8[8][256];           // 8 KB
    __shared__ unsigned s_prefix[4];
    __shared__ int s_want[4];
    __shared__ int s_cnt[4];
    __shared__ unsigned s_mn[4];
    __shared__ float s_qv[4];
    __shared__ float red[64];
    __shared__ float sh[8];

    const int pair = blockIdx.x;
    const int tid  = threadIdx.x;
    const int lane = tid & 63;
    const int wid  = tid >> 6;              // 16 waves
    const int b    = pair >> 1;
    const int dir  = pair & 1;
    const float* S1 = (dir == 0 ? x : y) + b * NV;
    const float* S2 = (dir == 0 ? y : x) + b * NV;

    // ---- Phase A: inline merge + residual keys into LDS ----
    #pragma unroll
    for (int step = 0; step < 4; ++step) {  // 4 * 1024 = 4096 queries
        const int q = step * 1024 + tid;
        float best = INFINITY; int bidx = 0;
        #pragma unroll 8
        for (int c = 0; c < NCCH; ++c) {    // independent loads, TLP-hidden
            float2 p = part[(size_t)(pair * NCCH + c) * N_ + q];
            if (p.x < best) { best = p.x; bidx = (int)p.y; }
        }
        keys[q * 3 + 0] = f2k(S1[q * 3 + 0] - S2[bidx * 3 + 0]);
        keys[q * 3 + 1] = f2k(S1[q * 3 + 1] - S2[bidx * 3 + 1]);
        keys[q * 3 + 2] = f2k(S1[q * 3 + 2] - S2[bidx * 3 + 2]);
    }
    if (tid < 4) {
        const float Qs[4] = {0.05f, 0.95f, 0.25f, 0.75f};
        s_prefix[tid] = 0u;
        s_want[tid]   = (int)floorf(Qs[tid] * (float)(NV - 1));
    }
    __syncthreads();

    // ---- Phase B: 4 radix passes (uint4-vectorized element scans) ----
    const uint4* k4 = (const uint4*)keys;   // NV/4 = 3072 = 3 * 1024 exact
    #pragma unroll 1
    for (int pass = 0; pass < 4; ++pass) {
        const int shift = 24 - 8 * pass;
        ((int*)hist8)[tid]             = 0; // 2048 ints, 2 stores/thread
        ((int*)hist8)[tid + TPB_TAIL]  = 0;
        __syncthreads();

        if (pass == 0) {
            int* h = hist8[wid & 7];        // wave-group-private copy
            for (int i = tid; i < NV / 4; i += TPB_TAIL) {
                uint4 kv = k4[i];
                atomicAdd(&h[kv.x >> 24], 1);
                atomicAdd(&h[kv.y >> 24], 1);
                atomicAdd(&h[kv.z >> 24], 1);
                atomicAdd(&h[kv.w >> 24], 1);
            }
        } else {
            const unsigned pmask = 0xFFFFFFFFu << (32 - 8 * pass);
            const unsigned pf0 = s_prefix[0], pf1 = s_prefix[1];
            const unsigned pf2 = s_prefix[2], pf3 = s_prefix[3];
            for (int i = tid; i < NV / 4; i += TPB_TAIL) {
                uint4 kv = k4[i];
                const unsigned ks[4] = {kv.x, kv.y, kv.z, kv.w};
                #pragma unroll
                for (int u = 0; u < 4; ++u) {
                    const unsigned k  = ks[u];
                    const unsigned kp = k & pmask;
                    const int bin = (int)((k >> shift) & 255u);
                    if (kp == pf0) atomicAdd(&hist8[0][bin], 1);
                    if (kp == pf1) atomicAdd(&hist8[1][bin], 1);
                    if (kp == pf2) atomicAdd(&hist8[2][bin], 1);
                    if (kp == pf3) atomicAdd(&hist8[3][bin], 1);
                }
            }
        }
        __syncthreads();

        // selection: wave t (t<4) scans quantile t's histogram
        if (wid < 4) {
            int c0 = 0, c1 = 0, c2 = 0, c3 = 0;
            if (pass == 0) {
                #pragma unroll
                for (int cp = 0; cp < 8; ++cp) {
                    c0 += hist8[cp][lane * 4 + 0]; c1 += hist8[cp][lane * 4 + 1];
                    c2 += hist8[cp][lane * 4 + 2]; c3 += hist8[cp][lane * 4 + 3];
                }
            } else {
                c0 = hist8[wid][lane * 4 + 0]; c1 = hist8[wid][lane * 4 + 1];
                c2 = hist8[wid][lane * 4 + 2]; c3 = hist8[wid][lane * 4 + 3];
            }
            const int want = s_want[wid];
            int s = c0 + c1 + c2 + c3;
            int pre = s;
            #pragma unroll
            for (int off = 1; off < 64; off <<= 1) {
                int u = __shfl_up(pre, off);
                if (lane >= off) pre += u;
            }
            const int excl = pre - s;
            const bool hit = (want >= excl) && (want < excl + s);
            unsigned long long m = __ballot(hit);
            const int hl = (int)(__ffsll(m) - 1);
            if (lane == hl) {
                int w = want - excl;
                int sel;
                if      (w < c0)           { sel = lane * 4 + 0; }
                else if (w < c0 + c1)      { sel = lane * 4 + 1; w -= c0; }
                else if (w < c0 + c1 + c2) { sel = lane * 4 + 2; w -= c0 + c1; }
                else                       { sel = lane * 4 + 3; w -= c0 + c1 + c2; }
                s_prefix[wid] |= ((unsigned)sel) << shift;
                s_want[wid] = w;
            }
        }
        __syncthreads();
    }

    // ---- Phase C: count(<=key0) and min(>key0) for all 4 quantiles ----
    if (tid < 4) { s_cnt[tid] = 0; s_mn[tid] = 0xFFFFFFFFu; }
    __syncthreads();
    const unsigned kq0 = s_prefix[0], kq1 = s_prefix[1];
    const unsigned kq2 = s_prefix[2], kq3 = s_prefix[3];
    int cnt0 = 0, cnt1 = 0, cnt2 = 0, cnt3 = 0;
    unsigned mn0 = 0xFFFFFFFFu, mn1 = 0xFFFFFFFFu, mn2 = 0xFFFFFFFFu, mn3 = 0xFFFFFFFFu;
    for (int i = tid; i < NV / 4; i += TPB_TAIL) {
        uint4 kv = k4[i];
        const unsigned ks[4] = {kv.x, kv.y, kv.z, kv.w};
        #pragma unroll
        for (int u = 0; u < 4; ++u) {
            const unsigned k = ks[u];
            if (k <= kq0) cnt0++; else if (k < mn0) mn0 = k;
            if (k <= kq1) cnt1++; else if (k < mn1) mn1 = k;
            if (k <= kq2) cnt2++; else if (k < mn2) mn2 = k;
            if (k <= kq3) cnt3++; else if (k < mn3) mn3 = k;
        }
    }
    #pragma unroll
    for (int off = 32; off > 0; off >>= 1) {
        cnt0 += __shfl_down(cnt0, off); cnt1 += __shfl_down(cnt1, off);
        cnt2 += __shfl_down(cnt2, off); cnt3 += __shfl_down(cnt3, off);
        unsigned u0 = __shfl_down(mn0, off); mn0 = u0 < mn0 ? u0 : mn0;
        unsigned u1 = __shfl_down(mn1, off); mn1 = u1 < mn1 ? u1 : mn1;
        unsigned u2 = __shfl_down(mn2, off); mn2 = u2 < mn2 ? u2 : mn2;
        unsigned u3 = __shfl_down(mn3, off); mn3 = u3 < mn3 ? u3 : mn3;
    }
    if (lane == 0) {
        atomicAdd(&s_cnt[0], cnt0); atomicMin(&s_mn[0], mn0);
        atomicAdd(&s_cnt[1], cnt1); atomicMin(&s_mn[1], mn1);
        atomicAdd(&s_cnt[2], cnt2); atomicMin(&s_mn[2], mn2);
        atomicAdd(&s_cnt[3], cnt3); atomicMin(&s_mn[3], mn3);
    }
    __syncthreads();
    if (tid < 4) {
        const float Qs[4] = {0.05f, 0.95f, 0.25f, 0.75f};
        const float pos = Qs[tid] * (float)(NV - 1);
        const int   k0  = (int)floorf(pos);
        const float fr  = pos - (float)k0;
        const float v0  = k2f(s_prefix[tid]);
        const float v1  = (s_cnt[tid] >= k0 + 2) ? v0 : k2f(s_mn[tid]);
        s_qv[tid] = v0 + fr * (v1 - v0);
    }
    __syncthreads();
    const float q0 = s_qv[0], q1 = s_qv[1], q2 = s_qv[2], q3 = s_qv[3];

    // ---- Phase D: masked two-pass mean/std from LDS keys ----
    float cb = 0.f, sb = 0.f, ce = 0.f, se = 0.f;
    for (int i = tid; i < NV / 4; i += TPB_TAIL) {
        uint4 kv = k4[i];
        const unsigned ks[4] = {kv.x, kv.y, kv.z, kv.w};
        #pragma unroll
        for (int u = 0; u < 4; ++u) {
            const float val = k2f(ks[u]);
            if ((val < q0) || (val > q1)) { cb += 1.f; sb += val; }
            if ((val > q2) && (val < q3)) { ce += 1.f; se += val; }
        }
    }
    #pragma unroll
    for (int off = 32; off > 0; off >>= 1) {
        cb += __shfl_down(cb, off); sb += __shfl_down(sb, off);
        ce += __shfl_down(ce, off); se += __shfl_down(se, off);
    }
    if (lane == 0) {
        red[wid * 4 + 0] = cb; red[wid * 4 + 1] = sb;
        red[wid * 4 + 2] = ce; red[wid * 4 + 3] = se;
    }
    __syncthreads();
    if (tid == 0) {
        float tcb = 0.f, tsb = 0.f, tce = 0.f, tse = 0.f;
        for (int w = 0; w < 16; ++w) {
            tcb += red[w * 4 + 0]; tsb += red[w * 4 + 1];
            tce += red[w * 4 + 2]; tse += red[w * 4 + 3];
        }
        sh[0] = tsb / tcb;  sh[1] = tse / tce;   // means
        sh[2] = tcb;        sh[3] = tce;         // counts
    }
    __syncthreads();
    const float mean_b = sh[0], mean_e = sh[1];
    const float nb = sh[2], ne = sh[3];

    float vb = 0.f, ve = 0.f;
    for (int i = tid; i < NV / 4; i += TPB_TAIL) {
        uint4 kv = k4[i];
        const unsigned ks[4] = {kv.x, kv.y, kv.z, kv.w};
        #pragma unroll
        for (int u = 0; u < 4; ++u) {
            const float val = k2f(ks[u]);
            if ((val < q0) || (val > q1)) { float d = val - mean_b; vb += d * d; }
            if ((val > q2) && (val < q3)) { float d = val - mean_e; ve += d * d; }
        }
    }
    #pragma unroll
    for (int off = 32; off > 0; off >>= 1) {
        vb += __shfl_down(vb, off);
        ve += __shfl_down(ve, off);
    }
    __syncthreads();
    if (lane == 0) { red[wid * 2 + 0] = vb; red[wid * 2 + 1] = ve; }
    __syncthreads();
    if (tid == 0) {
        float tvb = 0.f, tve = 0.f;
        for (int w = 0; w < 16; ++w) { tvb += red[w * 2 + 0]; tve += red[w * 2 + 1]; }
        stats[pair * 2 + 0] = sqrtf(tvb / (nb - 1.f));   // unbiased std, begin
        stats[pair * 2 + 1] = sqrtf(tve / (ne - 1.f));   // unbiased std, end
    }
}

// ---------------------------------------------------------------------------
// Kernel 3: per-batch max over directions, mean over batches.
// ---------------------------------------------------------------------------
__global__ void final_kernel(const float* __restrict__ stats, float* __restrict__ out) {
    if (threadIdx.x == 0 && blockIdx.x == 0) {
        float sb = 0.f, se = 0.f;
        for (int b = 0; b < B_; ++b) {
            float b1 = stats[(b * 2 + 0) * 2 + 0];
            float b2 = stats[(b * 2 + 1) * 2 + 0];
            float e1 = stats[(b * 2 + 0) * 2 + 1];
            float e2 = stats[(b * 2 + 1) * 2 + 1];
            sb += fmaxf(b1, b2);
            se += fmaxf(e1, e2);
        }
        out[0] = sb / (float)B_;
        out[1] = se / (float)B_;
    }
}

extern "C" void kernel_launch(void* const* d_in, const int* in_sizes, int n_in,
                              void* d_out, int out_size, void* d_ws, size_t ws_size,
                              hipStream_t stream) {
    const float* x = (const float*)d_in[0];
    const float* y = (const float*)d_in[1];
    float* out = (float*)d_out;

    // Workspace layout: [stats 16f][preX 256KB][preY 256KB][part 8MB]
    float*  stats = (float*)d_ws;
    float4* preX  = (float4*)(stats + 16);
    float4* preY  = preX + (size_t)B_ * N_;
    float4* part  = preY + (size_t)B_ * N_;

    prescale_kernel<<<dim3(B_ * N_ / 256, 2), 256, 0, stream>>>(x, y, preX, preY);
    nn_scalar_kernel<<<dim3(NCCH, N_ / 512, 8), 256, 0, stream>>>(x, y, preX, preY, part);
    fused_tail_kernel<<<8, TPB_TAIL, 0, stream>>>(x, y, (const float2*)part, stats);
    final_kernel<<<1, 64, 0, stream>>>(stats, out);
}

// Round 16
// 88.145 us; speedup vs baseline: 1.4020x; 1.4020x over previous
//
#include <hip/hip_runtime.h>
#include <math.h>

// Problem constants (fixed by the reference: B=4, N=4096, D=3)
constexpr int B_  = 4;
constexpr int N_  = 4096;
constexpr int NV  = N_ * 3;      // 12288 flattened residual elements per (batch,dir)
constexpr int NCCH = 64;         // candidate chunks
constexpr int CCH  = N_ / NCCH;  // 64 candidates per chunk
constexpr int QPT  = 4;          // queries per thread in the NN kernel
constexpr int TPB_TAIL = 1024;   // tail kernel block size

// float <-> monotonic uint key (order-preserving bijection on finite floats)
__device__ inline unsigned f2k(float f) {
    unsigned b = __float_as_uint(f);
    return b ^ ((unsigned)((int)b >> 31) | 0x80000000u);
}
__device__ inline float k2f(unsigned k) {
    unsigned b = (k & 0x80000000u) ? (k ^ 0x80000000u) : ~k;
    return __uint_as_float(b);
}

// ---------------------------------------------------------------------------
// Kernel 0: prescale candidates: pre[t] = {-2bx,-2by,-2bz,|b|^2}.
// grid = (B_*N_/256, 2): y-dim picks x or y input.
// ---------------------------------------------------------------------------
__global__ __launch_bounds__(256) void prescale_kernel(const float* __restrict__ x,
                                                       const float* __restrict__ y,
                                                       float4* __restrict__ preX,
                                                       float4* __restrict__ preY) {
    const int t = blockIdx.x * 256 + threadIdx.x;        // 0 .. B_*N_-1
    const float* src = blockIdx.y == 0 ? x : y;
    float4* dst      = blockIdx.y == 0 ? preX : preY;
    float bx = src[t * 3 + 0];
    float by = src[t * 3 + 1];
    float bz = src[t * 3 + 2];
    dst[t] = make_float4(-2.f * bx, -2.f * by, -2.f * bz,
                         bx * bx + by * by + bz * bz);
}

// ---------------------------------------------------------------------------
// Kernel 1: partial NN, scalar candidate loads, QPT=4.
// grid = (NCCH=64, N/(256*4)=4 qchunks, 8 pairs) = 2048 blocks = 8 blocks/CU
//      = 8 waves/SIMD (R13's proven TLP level).
// R14 instrumentation: QPT=1 ran 26.3us ~= 10 insts/pair (1 load + 6 VALU +
// ~3 bookkeeping). QPT=4 amortizes the load+bookkeeping over 4 queries ->
// ~7.5 insts/pair -> ~17us expected.  Register tile ~30 VGPR: fits 8 w/SIMD.
// Strict '<' keeps the FIRST minimal index (jnp.argmin tie-break).
// ---------------------------------------------------------------------------
__global__ __launch_bounds__(256) void nn_scalar_kernel(const float* __restrict__ x,
                                                        const float* __restrict__ y,
                                                        const float4* __restrict__ preX,
                                                        const float4* __restrict__ preY,
                                                        float4* __restrict__ part) {
    const int pair = blockIdx.z;
    const int b    = pair >> 1;
    const int dir  = pair & 1;              // 0: S1=x,S2=y ; 1: S1=y,S2=x
    const float*  S1 = (dir == 0 ? x : y) + b * NV;
    const float4* P2 = (dir == 0 ? preY : preX) + b * N_;
    const int cbase = blockIdx.x * CCH;

    // 4 contiguous queries: 12 floats = 3 aligned float4 loads (q0 % 4 == 0).
    const int q0 = blockIdx.y * 1024 + threadIdx.x * QPT;
    const float4* p4 = (const float4*)(S1 + q0 * 3);
    const float4 w0 = p4[0], w1 = p4[1], w2 = p4[2];
    const float ax0 = w0.x, ay0 = w0.y, az0 = w0.z;
    const float ax1 = w0.w, ay1 = w1.x, az1 = w1.y;
    const float ax2 = w1.z, ay2 = w1.w, az2 = w2.x;
    const float ax3 = w2.y, ay3 = w2.z, az3 = w2.w;

    float bd0 = INFINITY, bd1 = INFINITY, bd2 = INFINITY, bd3 = INFINITY;
    int idx0 = 0, idx1 = 0, idx2 = 0, idx3 = 0;
    #pragma unroll 8
    for (int j = 0; j < CCH; ++j) {
        const float4 c = P2[cbase + j];     // wave-uniform -> scalar load
        const int jg = cbase + j;
        // d2 = |b|^2 - 2 a.b  (3 FMAs per query on prescaled candidate)
        float d20 = fmaf(ax0, c.x, fmaf(ay0, c.y, fmaf(az0, c.z, c.w)));
        float d21 = fmaf(ax1, c.x, fmaf(ay1, c.y, fmaf(az1, c.z, c.w)));
        float d22 = fmaf(ax2, c.x, fmaf(ay2, c.y, fmaf(az2, c.z, c.w)));
        float d23 = fmaf(ax3, c.x, fmaf(ay3, c.y, fmaf(az3, c.z, c.w)));
        if (d20 < bd0) idx0 = jg;  bd0 = fminf(d20, bd0);
        if (d21 < bd1) idx1 = jg;  bd1 = fminf(d21, bd1);
        if (d22 < bd2) idx2 = jg;  bd2 = fminf(d22, bd2);
        if (d23 < bd3) idx3 = jg;  bd3 = fminf(d23, bd3);
    }

    // Two 16B stores for the 4 queries' (d2, idx).
    const size_t base = ((size_t)(pair * NCCH + blockIdx.x) * N_ + q0) >> 1;
    part[base + 0] = make_float4(bd0, (float)idx0, bd1, (float)idx1);
    part[base + 1] = make_float4(bd2, (float)idx2, bd3, (float)idx3);
}

// ---------------------------------------------------------------------------
// Kernel 2: parallel merge. grid = (N_/256, 8 pairs), block = 256 (WIDE --
// R8/R15 both proved the merge must NOT live in the 8-block tail).
// Unrolled independent dwordx2 loads, ascending chunk order + strict '<'
// == global first-index argmin.  Writes monotonic keys component-major
// (keys[pair][comp*N+q]) -- fully coalesced; quantile/std are
// order-invariant over the flattened set.
// ---------------------------------------------------------------------------
__global__ __launch_bounds__(256) void merge_keys_kernel(const float* __restrict__ x,
                                                         const float* __restrict__ y,
                                                         const float2* __restrict__ part,
                                                         unsigned* __restrict__ keys) {
    const int pair = blockIdx.y;
    const int b    = pair >> 1;
    const int dir  = pair & 1;
    const float* S1 = (dir == 0 ? x : y) + b * NV;
    const float* S2 = (dir == 0 ? y : x) + b * NV;
    const int q = blockIdx.x * 256 + threadIdx.x;

    float best = INFINITY;
    int bidx = 0;
    #pragma unroll 16
    for (int c = 0; c < NCCH; ++c) {
        float2 p = part[(size_t)(pair * NCCH + c) * N_ + q];
        if (p.x < best) { best = p.x; bidx = (int)p.y; }
    }
    unsigned* kp = keys + (size_t)pair * NV;
    kp[0 * N_ + q] = f2k(S1[q * 3 + 0] - S2[bidx * 3 + 0]);
    kp[1 * N_ + q] = f2k(S1[q * 3 + 1] - S2[bidx * 3 + 1]);
    kp[2 * N_ + q] = f2k(S1[q * 3 + 2] - S2[bidx * 3 + 2]);
}

// ---------------------------------------------------------------------------
// Kernel 3 (TAIL): one block per (batch,dir) pair, 1024 threads (16 waves).
//   A: stream keys into LDS (3 uint4 loads/thread, coalesced).
//   B: 4x 8-bit MSD radix-select for all four quantile order-stats at once
//      (uint4-vectorized scans; pass-1 hist has 8 wave-group-private copies).
//   C: fused count(<=key0)/min(>key0) -> linear-interp quantiles
//      (positions in fp32, identical to jnp.quantile).
//   D: two-pass masked mean/std from LDS keys (k2f exact inverse).
// ---------------------------------------------------------------------------
__global__ __launch_bounds__(TPB_TAIL) void tail_kernel(const unsigned* __restrict__ gkeys,
                                                        float* __restrict__ stats) {
    __shared__ unsigned keys[NV];           // 48 KB
    __shared__ int hist8[8][256];           // 8 KB
    __shared__ unsigned s_prefix[4];
    __shared__ int s_want[4];
    __shared__ int s_cnt[4];
    __shared__ unsigned s_mn[4];
    __shared__ float s_qv[4];
    __shared__ float red[64];
    __shared__ float sh[8];

    const int pair = blockIdx.x;
    const int tid  = threadIdx.x;
    const int lane = tid & 63;
    const int wid  = tid >> 6;              // 16 waves

    // ---- Phase A: stream keys into LDS ----
    const uint4* g4 = (const uint4*)(gkeys + (size_t)pair * NV);
    uint4* l4w = (uint4*)keys;
    #pragma unroll
    for (int i = 0; i < 3; ++i)             // NV/4 = 3072 = 3 * 1024 exact
        l4w[i * TPB_TAIL + tid] = g4[i * TPB_TAIL + tid];
    if (tid < 4) {
        const float Qs[4] = {0.05f, 0.95f, 0.25f, 0.75f};
        s_prefix[tid] = 0u;
        s_want[tid]   = (int)floorf(Qs[tid] * (float)(NV - 1));
    }
    __syncthreads();

    // ---- Phase B: 4 radix passes (uint4-vectorized element scans) ----
    const uint4* k4 = (const uint4*)keys;
    #pragma unroll 1
    for (int pass = 0; pass < 4; ++pass) {
        const int shift = 24 - 8 * pass;
        ((int*)hist8)[tid]             = 0; // 2048 ints, 2 stores/thread
        ((int*)hist8)[tid + TPB_TAIL]  = 0;
        __syncthreads();

        if (pass == 0) {
            int* h = hist8[wid & 7];        // wave-group-private copy
            for (int i = tid; i < NV / 4; i += TPB_TAIL) {
                uint4 kv = k4[i];
                atomicAdd(&h[kv.x >> 24], 1);
                atomicAdd(&h[kv.y >> 24], 1);
                atomicAdd(&h[kv.z >> 24], 1);
                atomicAdd(&h[kv.w >> 24], 1);
            }
        } else {
            const unsigned pmask = 0xFFFFFFFFu << (32 - 8 * pass);
            const unsigned pf0 = s_prefix[0], pf1 = s_prefix[1];
            const unsigned pf2 = s_prefix[2], pf3 = s_prefix[3];
            for (int i = tid; i < NV / 4; i += TPB_TAIL) {
                uint4 kv = k4[i];
                const unsigned ks[4] = {kv.x, kv.y, kv.z, kv.w};
                #pragma unroll
                for (int u = 0; u < 4; ++u) {
                    const unsigned k  = ks[u];
                    const unsigned kp = k & pmask;
                    const int bin = (int)((k >> shift) & 255u);
                    if (kp == pf0) atomicAdd(&hist8[0][bin], 1);
                    if (kp == pf1) atomicAdd(&hist8[1][bin], 1);
                    if (kp == pf2) atomicAdd(&hist8[2][bin], 1);
                    if (kp == pf3) atomicAdd(&hist8[3][bin], 1);
                }
            }
        }
        __syncthreads();

        // selection: wave t (t<4) scans quantile t's histogram
        if (wid < 4) {
            int c0 = 0, c1 = 0, c2 = 0, c3 = 0;
            if (pass == 0) {
                #pragma unroll
                for (int cp = 0; cp < 8; ++cp) {
                    c0 += hist8[cp][lane * 4 + 0]; c1 += hist8[cp][lane * 4 + 1];
                    c2 += hist8[cp][lane * 4 + 2]; c3 += hist8[cp][lane * 4 + 3];
                }
            } else {
                c0 = hist8[wid][lane * 4 + 0]; c1 = hist8[wid][lane * 4 + 1];
                c2 = hist8[wid][lane * 4 + 2]; c3 = hist8[wid][lane * 4 + 3];
            }
            const int want = s_want[wid];
            int s = c0 + c1 + c2 + c3;
            int pre = s;
            #pragma unroll
            for (int off = 1; off < 64; off <<= 1) {
                int u = __shfl_up(pre, off);
                if (lane >= off) pre += u;
            }
            const int excl = pre - s;
            const bool hit = (want >= excl) && (want < excl + s);
            unsigned long long m = __ballot(hit);
            const int hl = (int)(__ffsll(m) - 1);
            if (lane == hl) {
                int w = want - excl;
                int sel;
                if      (w < c0)           { sel = lane * 4 + 0; }
                else if (w < c0 + c1)      { sel = lane * 4 + 1; w -= c0; }
                else if (w < c0 + c1 + c2) { sel = lane * 4 + 2; w -= c0 + c1; }
                else                       { sel = lane * 4 + 3; w -= c0 + c1 + c2; }
                s_prefix[wid] |= ((unsigned)sel) << shift;
                s_want[wid] = w;
            }
        }
        __syncthreads();
    }

    // ---- Phase C: count(<=key0) and min(>key0) for all 4 quantiles ----
    if (tid < 4) { s_cnt[tid] = 0; s_mn[tid] = 0xFFFFFFFFu; }
    __syncthreads();
    const unsigned kq0 = s_prefix[0], kq1 = s_prefix[1];
    const unsigned kq2 = s_prefix[2], kq3 = s_prefix[3];
    int cnt0 = 0, cnt1 = 0, cnt2 = 0, cnt3 = 0;
    unsigned mn0 = 0xFFFFFFFFu, mn1 = 0xFFFFFFFFu, mn2 = 0xFFFFFFFFu, mn3 = 0xFFFFFFFFu;
    for (int i = tid; i < NV / 4; i += TPB_TAIL) {
        uint4 kv = k4[i];
        const unsigned ks[4] = {kv.x, kv.y, kv.z, kv.w};
        #pragma unroll
        for (int u = 0; u < 4; ++u) {
            const unsigned k = ks[u];
            if (k <= kq0) cnt0++; else if (k < mn0) mn0 = k;
            if (k <= kq1) cnt1++; else if (k < mn1) mn1 = k;
            if (k <= kq2) cnt2++; else if (k < mn2) mn2 = k;
            if (k <= kq3) cnt3++; else if (k < mn3) mn3 = k;
        }
    }
    #pragma unroll
    for (int off = 32; off > 0; off >>= 1) {
        cnt0 += __shfl_down(cnt0, off); cnt1 += __shfl_down(cnt1, off);
        cnt2 += __shfl_down(cnt2, off); cnt3 += __shfl_down(cnt3, off);
        unsigned u0 = __shfl_down(mn0, off); mn0 = u0 < mn0 ? u0 : mn0;
        unsigned u1 = __shfl_down(mn1, off); mn1 = u1 < mn1 ? u1 : mn1;
        unsigned u2 = __shfl_down(mn2, off); mn2 = u2 < mn2 ? u2 : mn2;
        unsigned u3 = __shfl_down(mn3, off); mn3 = u3 < mn3 ? u3 : mn3;
    }
    if (lane == 0) {
        atomicAdd(&s_cnt[0], cnt0); atomicMin(&s_mn[0], mn0);
        atomicAdd(&s_cnt[1], cnt1); atomicMin(&s_mn[1], mn1);
        atomicAdd(&s_cnt[2], cnt2); atomicMin(&s_mn[2], mn2);
        atomicAdd(&s_cnt[3], cnt3); atomicMin(&s_mn[3], mn3);
    }
    __syncthreads();
    if (tid < 4) {
        const float Qs[4] = {0.05f, 0.95f, 0.25f, 0.75f};
        const float pos = Qs[tid] * (float)(NV - 1);
        const int   k0  = (int)floorf(pos);
        const float fr  = pos - (float)k0;
        const float v0  = k2f(s_prefix[tid]);
        const float v1  = (s_cnt[tid] >= k0 + 2) ? v0 : k2f(s_mn[tid]);
        s_qv[tid] = v0 + fr * (v1 - v0);
    }
    __syncthreads();
    const float q0 = s_qv[0], q1 = s_qv[1], q2 = s_qv[2], q3 = s_qv[3];

    // ---- Phase D: masked two-pass mean/std from LDS keys ----
    float cb = 0.f, sb = 0.f, ce = 0.f, se = 0.f;
    for (int i = tid; i < NV / 4; i += TPB_TAIL) {
        uint4 kv = k4[i];
        const unsigned ks[4] = {kv.x, kv.y, kv.z, kv.w};
        #pragma unroll
        for (int u = 0; u < 4; ++u) {
            const float val = k2f(ks[u]);
            if ((val < q0) || (val > q1)) { cb += 1.f; sb += val; }
            if ((val > q2) && (val < q3)) { ce += 1.f; se += val; }
        }
    }
    #pragma unroll
    for (int off = 32; off > 0; off >>= 1) {
        cb += __shfl_down(cb, off); sb += __shfl_down(sb, off);
        ce += __shfl_down(ce, off); se += __shfl_down(se, off);
    }
    if (lane == 0) {
        red[wid * 4 + 0] = cb; red[wid * 4 + 1] = sb;
        red[wid * 4 + 2] = ce; red[wid * 4 + 3] = se;
    }
    __syncthreads();
    if (tid == 0) {
        float tcb = 0.f, tsb = 0.f, tce = 0.f, tse = 0.f;
        for (int w = 0; w < 16; ++w) {
            tcb += red[w * 4 + 0]; tsb += red[w * 4 + 1];
            tce += red[w * 4 + 2]; tse += red[w * 4 + 3];
        }
        sh[0] = tsb / tcb;  sh[1] = tse / tce;   // means
        sh[2] = tcb;        sh[3] = tce;         // counts
    }
    __syncthreads();
    const float mean_b = sh[0], mean_e = sh[1];
    const float nb = sh[2], ne = sh[3];

    float vb = 0.f, ve = 0.f;
    for (int i = tid; i < NV / 4; i += TPB_TAIL) {
        uint4 kv = k4[i];
        const unsigned ks[4] = {kv.x, kv.y, kv.z, kv.w};
        #pragma unroll
        for (int u = 0; u < 4; ++u) {
            const float val = k2f(ks[u]);
            if ((val < q0) || (val > q1)) { float d = val - mean_b; vb += d * d; }
            if ((val > q2) && (val < q3)) { float d = val - mean_e; ve += d * d; }
        }
    }
    #pragma unroll
    for (int off = 32; off > 0; off >>= 1) {
        vb += __shfl_down(vb, off);
        ve += __shfl_down(ve, off);
    }
    __syncthreads();
    if (lane == 0) { red[wid * 2 + 0] = vb; red[wid * 2 + 1] = ve; }
    __syncthreads();
    if (tid == 0) {
        float tvb = 0.f, tve = 0.f;
        for (int w = 0; w < 16; ++w) { tvb += red[w * 2 + 0]; tve += red[w * 2 + 1]; }
        stats[pair * 2 + 0] = sqrtf(tvb / (nb - 1.f));   // unbiased std, begin
        stats[pair * 2 + 1] = sqrtf(tve / (ne - 1.f));   // unbiased std, end
    }
}

// ---------------------------------------------------------------------------
// Kernel 4: per-batch max over directions, mean over batches.
// ---------------------------------------------------------------------------
__global__ void final_kernel(const float* __restrict__ stats, float* __restrict__ out) {
    if (threadIdx.x == 0 && blockIdx.x == 0) {
        float sb = 0.f, se = 0.f;
        for (int b = 0; b < B_; ++b) {
            float b1 = stats[(b * 2 + 0) * 2 + 0];
            float b2 = stats[(b * 2 + 1) * 2 + 0];
            float e1 = stats[(b * 2 + 0) * 2 + 1];
            float e2 = stats[(b * 2 + 1) * 2 + 1];
            sb += fmaxf(b1, b2);
            se += fmaxf(e1, e2);
        }
        out[0] = sb / (float)B_;
        out[1] = se / (float)B_;
    }
}

extern "C" void kernel_launch(void* const* d_in, const int* in_sizes, int n_in,
                              void* d_out, int out_size, void* d_ws, size_t ws_size,
                              hipStream_t stream) {
    const float* x = (const float*)d_in[0];
    const float* y = (const float*)d_in[1];
    float* out = (float*)d_out;

    // Workspace: [keys 384KB][stats 16f][preX 256KB][preY 256KB][part 16.8MB]
    unsigned* keys  = (unsigned*)d_ws;
    float*    stats = (float*)(keys + (size_t)8 * NV);
    float4*   preX  = (float4*)(stats + 16);
    float4*   preY  = preX + (size_t)B_ * N_;
    float4*   part  = preY + (size_t)B_ * N_;

    prescale_kernel<<<dim3(B_ * N_ / 256, 2), 256, 0, stream>>>(x, y, preX, preY);
    nn_scalar_kernel<<<dim3(NCCH, N_ / 1024, 8), 256, 0, stream>>>(x, y, preX, preY, part);
    merge_keys_kernel<<<dim3(N_ / 256, 8), 256, 0, stream>>>(x, y, (const float2*)part, keys);
    tail_kernel<<<8, TPB_TAIL, 0, stream>>>(keys, stats);
    final_kernel<<<1, 64, 0, stream>>>(stats, out);
}

// Round 18
// 85.302 us; speedup vs baseline: 1.4487x; 1.0333x over previous
//
#include <hip/hip_runtime.h>
#include <math.h>

// Problem constants (fixed by the reference: B=4, N=4096, D=3)
constexpr int B_  = 4;
constexpr int N_  = 4096;
constexpr int NV  = N_ * 3;      // 12288 flattened residual elements per (batch,dir)
constexpr int NCCH = 16;         // candidate chunks (R13-proven config)
constexpr int CCH  = N_ / NCCH;  // 256 candidates per chunk
constexpr int TPB_TAIL = 1024;   // tail kernel block size

// float <-> monotonic uint key (order-preserving bijection on finite floats)
__device__ inline unsigned f2k(float f) {
    unsigned b = __float_as_uint(f);
    return b ^ ((unsigned)((int)b >> 31) | 0x80000000u);
}
__device__ inline float k2f(unsigned k) {
    unsigned b = (k & 0x80000000u) ? (k ^ 0x80000000u) : ~k;
    return __uint_as_float(b);
}

// ---------------------------------------------------------------------------
// Kernel 0: prescale candidates: pre[t] = {-2bx,-2by,-2bz,|b|^2}.
// grid = (B_*N_/256, 2): y-dim picks x or y input.
// ---------------------------------------------------------------------------
__global__ __launch_bounds__(256) void prescale_kernel(const float* __restrict__ x,
                                                       const float* __restrict__ y,
                                                       float4* __restrict__ preX,
                                                       float4* __restrict__ preY) {
    const int t = blockIdx.x * 256 + threadIdx.x;        // 0 .. B_*N_-1
    const float* src = blockIdx.y == 0 ? x : y;
    float4* dst      = blockIdx.y == 0 ? preX : preY;
    float bx = src[t * 3 + 0];
    float by = src[t * 3 + 1];
    float bz = src[t * 3 + 2];
    dst[t] = make_float4(-2.f * bx, -2.f * by, -2.f * bz,
                         bx * bx + by * by + bz * bz);
}

// ---------------------------------------------------------------------------
// Kernel 1: partial NN, scalar candidate loads, QPT=1 (R13 config: 26.3us
// measured via R14 double-launch; QPT=2/4/8 variants all regressed).
// grid = (NCCH=16, N/256 qchunks, 8 pairs) = 2048 blocks = 8 blocks/CU.
// Strict '<' keeps the FIRST minimal index (jnp.argmin tie-break).
// ---------------------------------------------------------------------------
__global__ __launch_bounds__(256) void nn_scalar_kernel(const float* __restrict__ x,
                                                        const float* __restrict__ y,
                                                        const float4* __restrict__ preX,
                                                        const float4* __restrict__ preY,
                                                        float2* __restrict__ part) {
    const int pair = blockIdx.z;
    const int b    = pair >> 1;
    const int dir  = pair & 1;              // 0: S1=x,S2=y ; 1: S1=y,S2=x
    const float*  S1 = (dir == 0 ? x : y) + b * NV;
    const float4* P2 = (dir == 0 ? preY : preX) + b * N_;
    const int cbase = blockIdx.x * CCH;

    const int q = blockIdx.y * 256 + threadIdx.x;
    const float ax = S1[q * 3 + 0];
    const float ay = S1[q * 3 + 1];
    const float az = S1[q * 3 + 2];

    float bd = INFINITY;
    int idx = 0;
    #pragma unroll 16
    for (int j = 0; j < CCH; ++j) {
        const float4 c = P2[cbase + j];     // wave-uniform -> scalar load
        // d2 = |b|^2 - 2 a.b  (3 FMAs; candidate components are SGPR operands)
        float d2 = fmaf(ax, c.x, fmaf(ay, c.y, fmaf(az, c.z, c.w)));
        if (d2 < bd) idx = cbase + j;       // v_cmp + v_cndmask
        bd = fminf(d2, bd);                 // v_min
    }
    part[(size_t)(pair * NCCH + blockIdx.x) * N_ + q] = make_float2(bd, (float)idx);
}

// ---------------------------------------------------------------------------
// Kernel 2: parallel merge. grid = (N_/256, 8 pairs), block = 256 (WIDE --
// R8/R15 both proved the merge must NOT live in the 8-block tail).
// NCCH fully unrolled -> independent dwordx2 loads, ascending chunk order +
// strict '<' == global first-index argmin.  Writes monotonic keys
// component-major (keys[pair][comp*N+q]) -- fully coalesced; quantile/std
// are order-invariant over the flattened set.
// ---------------------------------------------------------------------------
__global__ __launch_bounds__(256) void merge_keys_kernel(const float* __restrict__ x,
                                                         const float* __restrict__ y,
                                                         const float2* __restrict__ part,
                                                         unsigned* __restrict__ keys) {
    const int pair = blockIdx.y;
    const int b    = pair >> 1;
    const int dir  = pair & 1;
    const float* S1 = (dir == 0 ? x : y) + b * NV;
    const float* S2 = (dir == 0 ? y : x) + b * NV;
    const int q = blockIdx.x * 256 + threadIdx.x;

    float best = INFINITY;
    int bidx = 0;
    #pragma unroll
    for (int c = 0; c < NCCH; ++c) {
        float2 p = part[(size_t)(pair * NCCH + c) * N_ + q];
        if (p.x < best) { best = p.x; bidx = (int)p.y; }
    }
    unsigned* kp = keys + (size_t)pair * NV;
    kp[0 * N_ + q] = f2k(S1[q * 3 + 0] - S2[bidx * 3 + 0]);
    kp[1 * N_ + q] = f2k(S1[q * 3 + 1] - S2[bidx * 3 + 1]);
    kp[2 * N_ + q] = f2k(S1[q * 3 + 2] - S2[bidx * 3 + 2]);
}

// ---------------------------------------------------------------------------
// Kernel 3 (TAIL): one block per (batch,dir) pair, 1024 threads (16 waves).
// INSTRUMENTATION NOTE (round 18 resubmit): launched TWICE. Pure function of
// gkeys -> stats, so the double launch is deterministic/output-identical;
// dur gains exactly (t_tail + one launch gap).  Decision rule:
// dur >= 84 -> tail is the second bottleneck; dur <= 78 -> launch gaps are.
// ---------------------------------------------------------------------------
__global__ __launch_bounds__(TPB_TAIL) void tail_kernel(const unsigned* __restrict__ gkeys,
                                                        float* __restrict__ stats) {
    __shared__ unsigned keys[NV];           // 48 KB
    __shared__ int hist8[8][256];           // 8 KB
    __shared__ unsigned s_prefix[4];
    __shared__ int s_want[4];
    __shared__ int s_cnt[4];
    __shared__ unsigned s_mn[4];
    __shared__ float s_qv[4];
    __shared__ float red[64];
    __shared__ float sh[8];

    const int pair = blockIdx.x;
    const int tid  = threadIdx.x;
    const int lane = tid & 63;
    const int wid  = tid >> 6;              // 16 waves

    // ---- Phase A: stream keys into LDS ----
    const uint4* g4 = (const uint4*)(gkeys + (size_t)pair * NV);
    uint4* l4w = (uint4*)keys;
    #pragma unroll
    for (int i = 0; i < 3; ++i)             // NV/4 = 3072 = 3 * 1024 exact
        l4w[i * TPB_TAIL + tid] = g4[i * TPB_TAIL + tid];
    if (tid < 4) {
        const float Qs[4] = {0.05f, 0.95f, 0.25f, 0.75f};
        s_prefix[tid] = 0u;
        s_want[tid]   = (int)floorf(Qs[tid] * (float)(NV - 1));
    }
    __syncthreads();

    // ---- Phase B: 4 radix passes (uint4-vectorized element scans) ----
    const uint4* k4 = (const uint4*)keys;
    #pragma unroll 1
    for (int pass = 0; pass < 4; ++pass) {
        const int shift = 24 - 8 * pass;
        ((int*)hist8)[tid]             = 0; // 2048 ints, 2 stores/thread
        ((int*)hist8)[tid + TPB_TAIL]  = 0;
        __syncthreads();

        if (pass == 0) {
            int* h = hist8[wid & 7];        // wave-group-private copy
            for (int i = tid; i < NV / 4; i += TPB_TAIL) {
                uint4 kv = k4[i];
                atomicAdd(&h[kv.x >> 24], 1);
                atomicAdd(&h[kv.y >> 24], 1);
                atomicAdd(&h[kv.z >> 24], 1);
                atomicAdd(&h[kv.w >> 24], 1);
            }
        } else {
            const unsigned pmask = 0xFFFFFFFFu << (32 - 8 * pass);
            const unsigned pf0 = s_prefix[0], pf1 = s_prefix[1];
            const unsigned pf2 = s_prefix[2], pf3 = s_prefix[3];
            for (int i = tid; i < NV / 4; i += TPB_TAIL) {
                uint4 kv = k4[i];
                const unsigned ks[4] = {kv.x, kv.y, kv.z, kv.w};
                #pragma unroll
                for (int u = 0; u < 4; ++u) {
                    const unsigned k  = ks[u];
                    const unsigned kp = k & pmask;
                    const int bin = (int)((k >> shift) & 255u);
                    if (kp == pf0) atomicAdd(&hist8[0][bin], 1);
                    if (kp == pf1) atomicAdd(&hist8[1][bin], 1);
                    if (kp == pf2) atomicAdd(&hist8[2][bin], 1);
                    if (kp == pf3) atomicAdd(&hist8[3][bin], 1);
                }
            }
        }
        __syncthreads();

        // selection: wave t (t<4) scans quantile t's histogram
        if (wid < 4) {
            int c0 = 0, c1 = 0, c2 = 0, c3 = 0;
            if (pass == 0) {
                #pragma unroll
                for (int cp = 0; cp < 8; ++cp) {
                    c0 += hist8[cp][lane * 4 + 0]; c1 += hist8[cp][lane * 4 + 1];
                    c2 += hist8[cp][lane * 4 + 2]; c3 += hist8[cp][lane * 4 + 3];
                }
            } else {
                c0 = hist8[wid][lane * 4 + 0]; c1 = hist8[wid][lane * 4 + 1];
                c2 = hist8[wid][lane * 4 + 2]; c3 = hist8[wid][lane * 4 + 3];
            }
            const int want = s_want[wid];
            int s = c0 + c1 + c2 + c3;
            int pre = s;
            #pragma unroll
            for (int off = 1; off < 64; off <<= 1) {
                int u = __shfl_up(pre, off);
                if (lane >= off) pre += u;
            }
            const int excl = pre - s;
            const bool hit = (want >= excl) && (want < excl + s);
            unsigned long long m = __ballot(hit);
            const int hl = (int)(__ffsll(m) - 1);
            if (lane == hl) {
                int w = want - excl;
                int sel;
                if      (w < c0)           { sel = lane * 4 + 0; }
                else if (w < c0 + c1)      { sel = lane * 4 + 1; w -= c0; }
                else if (w < c0 + c1 + c2) { sel = lane * 4 + 2; w -= c0 + c1; }
                else                       { sel = lane * 4 + 3; w -= c0 + c1 + c2; }
                s_prefix[wid] |= ((unsigned)sel) << shift;
                s_want[wid] = w;
            }
        }
        __syncthreads();
    }

    // ---- Phase C: count(<=key0) and min(>key0) for all 4 quantiles ----
    if (tid < 4) { s_cnt[tid] = 0; s_mn[tid] = 0xFFFFFFFFu; }
    __syncthreads();
    const unsigned kq0 = s_prefix[0], kq1 = s_prefix[1];
    const unsigned kq2 = s_prefix[2], kq3 = s_prefix[3];
    int cnt0 = 0, cnt1 = 0, cnt2 = 0, cnt3 = 0;
    unsigned mn0 = 0xFFFFFFFFu, mn1 = 0xFFFFFFFFu, mn2 = 0xFFFFFFFFu, mn3 = 0xFFFFFFFFu;
    for (int i = tid; i < NV / 4; i += TPB_TAIL) {
        uint4 kv = k4[i];
        const unsigned ks[4] = {kv.x, kv.y, kv.z, kv.w};
        #pragma unroll
        for (int u = 0; u < 4; ++u) {
            const unsigned k = ks[u];
            if (k <= kq0) cnt0++; else if (k < mn0) mn0 = k;
            if (k <= kq1) cnt1++; else if (k < mn1) mn1 = k;
            if (k <= kq2) cnt2++; else if (k < mn2) mn2 = k;
            if (k <= kq3) cnt3++; else if (k < mn3) mn3 = k;
        }
    }
    #pragma unroll
    for (int off = 32; off > 0; off >>= 1) {
        cnt0 += __shfl_down(cnt0, off); cnt1 += __shfl_down(cnt1, off);
        cnt2 += __shfl_down(cnt2, off); cnt3 += __shfl_down(cnt3, off);
        unsigned u0 = __shfl_down(mn0, off); mn0 = u0 < mn0 ? u0 : mn0;
        unsigned u1 = __shfl_down(mn1, off); mn1 = u1 < mn1 ? u1 : mn1;
        unsigned u2 = __shfl_down(mn2, off); mn2 = u2 < mn2 ? u2 : mn2;
        unsigned u3 = __shfl_down(mn3, off); mn3 = u3 < mn3 ? u3 : mn3;
    }
    if (lane == 0) {
        atomicAdd(&s_cnt[0], cnt0); atomicMin(&s_mn[0], mn0);
        atomicAdd(&s_cnt[1], cnt1); atomicMin(&s_mn[1], mn1);
        atomicAdd(&s_cnt[2], cnt2); atomicMin(&s_mn[2], mn2);
        atomicAdd(&s_cnt[3], cnt3); atomicMin(&s_mn[3], mn3);
    }
    __syncthreads();
    if (tid < 4) {
        const float Qs[4] = {0.05f, 0.95f, 0.25f, 0.75f};
        const float pos = Qs[tid] * (float)(NV - 1);
        const int   k0  = (int)floorf(pos);
        const float fr  = pos - (float)k0;
        const float v0  = k2f(s_prefix[tid]);
        const float v1  = (s_cnt[tid] >= k0 + 2) ? v0 : k2f(s_mn[tid]);
        s_qv[tid] = v0 + fr * (v1 - v0);
    }
    __syncthreads();
    const float q0 = s_qv[0], q1 = s_qv[1], q2 = s_qv[2], q3 = s_qv[3];

    // ---- Phase D: masked two-pass mean/std from LDS keys ----
    float cb = 0.f, sb = 0.f, ce = 0.f, se = 0.f;
    for (int i = tid; i < NV / 4; i += TPB_TAIL) {
        uint4 kv = k4[i];
        const unsigned ks[4] = {kv.x, kv.y, kv.z, kv.w};
        #pragma unroll
        for (int u = 0; u < 4; ++u) {
            const float val = k2f(ks[u]);
            if ((val < q0) || (val > q1)) { cb += 1.f; sb += val; }
            if ((val > q2) && (val < q3)) { ce += 1.f; se += val; }
        }
    }
    #pragma unroll
    for (int off = 32; off > 0; off >>= 1) {
        cb += __shfl_down(cb, off); sb += __shfl_down(sb, off);
        ce += __shfl_down(ce, off); se += __shfl_down(se, off);
    }
    if (lane == 0) {
        red[wid * 4 + 0] = cb; red[wid * 4 + 1] = sb;
        red[wid * 4 + 2] = ce; red[wid * 4 + 3] = se;
    }
    __syncthreads();
    if (tid == 0) {
        float tcb = 0.f, tsb = 0.f, tce = 0.f, tse = 0.f;
        for (int w = 0; w < 16; ++w) {
            tcb += red[w * 4 + 0]; tsb += red[w * 4 + 1];
            tce += red[w * 4 + 2]; tse += red[w * 4 + 3];
        }
        sh[0] = tsb / tcb;  sh[1] = tse / tce;   // means
        sh[2] = tcb;        sh[3] = tce;         // counts
    }
    __syncthreads();
    const float mean_b = sh[0], mean_e = sh[1];
    const float nb = sh[2], ne = sh[3];

    float vb = 0.f, ve = 0.f;
    for (int i = tid; i < NV / 4; i += TPB_TAIL) {
        uint4 kv = k4[i];
        const unsigned ks[4] = {kv.x, kv.y, kv.z, kv.w};
        #pragma unroll
        for (int u = 0; u < 4; ++u) {
            const float val = k2f(ks[u]);
            if ((val < q0) || (val > q1)) { float d = val - mean_b; vb += d * d; }
            if ((val > q2) && (val < q3)) { float d = val - mean_e; ve += d * d; }
        }
    }
    #pragma unroll
    for (int off = 32; off > 0; off >>= 1) {
        vb += __shfl_down(vb, off);
        ve += __shfl_down(ve, off);
    }
    __syncthreads();
    if (lane == 0) { red[wid * 2 + 0] = vb; red[wid * 2 + 1] = ve; }
    __syncthreads();
    if (tid == 0) {
        float tvb = 0.f, tve = 0.f;
        for (int w = 0; w < 16; ++w) { tvb += red[w * 2 + 0]; tve += red[w * 2 + 1]; }
        stats[pair * 2 + 0] = sqrtf(tvb / (nb - 1.f));   // unbiased std, begin
        stats[pair * 2 + 1] = sqrtf(tve / (ne - 1.f));   // unbiased std, end
    }
}

// ---------------------------------------------------------------------------
// Kernel 4: per-batch max over directions, mean over batches.
// ---------------------------------------------------------------------------
__global__ void final_kernel(const float* __restrict__ stats, float* __restrict__ out) {
    if (threadIdx.x == 0 && blockIdx.x == 0) {
        float sb = 0.f, se = 0.f;
        for (int b = 0; b < B_; ++b) {
            float b1 = stats[(b * 2 + 0) * 2 + 0];
            float b2 = stats[(b * 2 + 1) * 2 + 0];
            float e1 = stats[(b * 2 + 0) * 2 + 1];
            float e2 = stats[(b * 2 + 1) * 2 + 1];
            sb += fmaxf(b1, b2);
            se += fmaxf(e1, e2);
        }
        out[0] = sb / (float)B_;
        out[1] = se / (float)B_;
    }
}

extern "C" void kernel_launch(void* const* d_in, const int* in_sizes, int n_in,
                              void* d_out, int out_size, void* d_ws, size_t ws_size,
                              hipStream_t stream) {
    const float* x = (const float*)d_in[0];
    const float* y = (const float*)d_in[1];
    float* out = (float*)d_out;

    // Workspace: [keys 384KB][stats 16f][preX 256KB][preY 256KB][part 4.2MB]
    unsigned* keys  = (unsigned*)d_ws;
    float*    stats = (float*)(keys + (size_t)8 * NV);
    float4*   preX  = (float4*)(stats + 16);
    float4*   preY  = preX + (size_t)B_ * N_;
    float2*   part  = (float2*)(preY + (size_t)B_ * N_);

    prescale_kernel<<<dim3(B_ * N_ / 256, 2), 256, 0, stream>>>(x, y, preX, preY);
    nn_scalar_kernel<<<dim3(NCCH, N_ / 256, 8), 256, 0, stream>>>(x, y, preX, preY, part);
    merge_keys_kernel<<<dim3(N_ / 256, 8), 256, 0, stream>>>(x, y, part, keys);
    // INSTRUMENTATION: tail launched twice (pure function, identical output).
    // dur_us - 65.6 ~= t_tail + one launch gap. See decision rule above.
    tail_kernel<<<8, TPB_TAIL, 0, stream>>>(keys, stats);
    tail_kernel<<<8, TPB_TAIL, 0, stream>>>(keys, stats);
    final_kernel<<<1, 64, 0, stream>>>(stats, out);
}

// Round 19
// 65.695 us; speedup vs baseline: 1.8811x; 1.2984x over previous
//
#include <hip/hip_runtime.h>
#include <math.h>

// Problem constants (fixed by the reference: B=4, N=4096, D=3)
constexpr int B_  = 4;
constexpr int N_  = 4096;
constexpr int NV  = N_ * 3;      // 12288 flattened residual elements per (batch,dir)
constexpr int NCCH = 16;         // candidate chunks (R13-proven config)
constexpr int CCH  = N_ / NCCH;  // 256 candidates per chunk
constexpr int TPB_TAIL = 1024;   // tail kernel block size

// float <-> monotonic uint key (order-preserving bijection on finite floats)
__device__ inline unsigned f2k(float f) {
    unsigned b = __float_as_uint(f);
    return b ^ ((unsigned)((int)b >> 31) | 0x80000000u);
}
__device__ inline float k2f(unsigned k) {
    unsigned b = (k & 0x80000000u) ? (k ^ 0x80000000u) : ~k;
    return __uint_as_float(b);
}

// ---------------------------------------------------------------------------
// Kernel 0: prescale candidates + zero the tail completion counter.
// grid = (B_*N_/256, 2): y-dim picks x or y input.
// ---------------------------------------------------------------------------
__global__ __launch_bounds__(256) void prescale_kernel(const float* __restrict__ x,
                                                       const float* __restrict__ y,
                                                       float4* __restrict__ preX,
                                                       float4* __restrict__ preY,
                                                       unsigned* __restrict__ done_cnt) {
    if (blockIdx.x == 0 && blockIdx.y == 0 && threadIdx.x == 0) *done_cnt = 0u;
    const int t = blockIdx.x * 256 + threadIdx.x;        // 0 .. B_*N_-1
    const float* src = blockIdx.y == 0 ? x : y;
    float4* dst      = blockIdx.y == 0 ? preX : preY;
    float bx = src[t * 3 + 0];
    float by = src[t * 3 + 1];
    float bz = src[t * 3 + 2];
    dst[t] = make_float4(-2.f * bx, -2.f * by, -2.f * bz,
                         bx * bx + by * by + bz * bz);
}

// ---------------------------------------------------------------------------
// Kernel 1: partial NN, scalar candidate loads, QPT=1 (R13 config: 26.3us
// measured via R14 double-launch; QPT=2/4/8 variants all regressed).
// grid = (NCCH=16, N/256 qchunks, 8 pairs) = 2048 blocks = 8 blocks/CU.
// Strict '<' keeps the FIRST minimal index (jnp.argmin tie-break).
// ---------------------------------------------------------------------------
__global__ __launch_bounds__(256) void nn_scalar_kernel(const float* __restrict__ x,
                                                        const float* __restrict__ y,
                                                        const float4* __restrict__ preX,
                                                        const float4* __restrict__ preY,
                                                        float2* __restrict__ part) {
    const int pair = blockIdx.z;
    const int b    = pair >> 1;
    const int dir  = pair & 1;              // 0: S1=x,S2=y ; 1: S1=y,S2=x
    const float*  S1 = (dir == 0 ? x : y) + b * NV;
    const float4* P2 = (dir == 0 ? preY : preX) + b * N_;
    const int cbase = blockIdx.x * CCH;

    const int q = blockIdx.y * 256 + threadIdx.x;
    const float ax = S1[q * 3 + 0];
    const float ay = S1[q * 3 + 1];
    const float az = S1[q * 3 + 2];

    float bd = INFINITY;
    int idx = 0;
    #pragma unroll 16
    for (int j = 0; j < CCH; ++j) {
        const float4 c = P2[cbase + j];     // wave-uniform -> scalar load
        // d2 = |b|^2 - 2 a.b  (3 FMAs; candidate components are SGPR operands)
        float d2 = fmaf(ax, c.x, fmaf(ay, c.y, fmaf(az, c.z, c.w)));
        if (d2 < bd) idx = cbase + j;       // v_cmp + v_cndmask
        bd = fminf(d2, bd);                 // v_min
    }
    part[(size_t)(pair * NCCH + blockIdx.x) * N_ + q] = make_float2(bd, (float)idx);
}

// ---------------------------------------------------------------------------
// Kernel 2: parallel merge. grid = (N_/256, 8 pairs), block = 256 (WIDE --
// R8/R15 both proved the merge must NOT live in the 8-block tail).
// NCCH fully unrolled -> independent dwordx2 loads, ascending chunk order +
// strict '<' == global first-index argmin.  Writes monotonic keys
// component-major (keys[pair][comp*N+q]) -- fully coalesced.
// ---------------------------------------------------------------------------
__global__ __launch_bounds__(256) void merge_keys_kernel(const float* __restrict__ x,
                                                         const float* __restrict__ y,
                                                         const float2* __restrict__ part,
                                                         unsigned* __restrict__ keys) {
    const int pair = blockIdx.y;
    const int b    = pair >> 1;
    const int dir  = pair & 1;
    const float* S1 = (dir == 0 ? x : y) + b * NV;
    const float* S2 = (dir == 0 ? y : x) + b * NV;
    const int q = blockIdx.x * 256 + threadIdx.x;

    float best = INFINITY;
    int bidx = 0;
    #pragma unroll
    for (int c = 0; c < NCCH; ++c) {
        float2 p = part[(size_t)(pair * NCCH + c) * N_ + q];
        if (p.x < best) { best = p.x; bidx = (int)p.y; }
    }
    unsigned* kp = keys + (size_t)pair * NV;
    kp[0 * N_ + q] = f2k(S1[q * 3 + 0] - S2[bidx * 3 + 0]);
    kp[1 * N_ + q] = f2k(S1[q * 3 + 1] - S2[bidx * 3 + 1]);
    kp[2 * N_ + q] = f2k(S1[q * 3 + 2] - S2[bidx * 3 + 2]);
}

// ---------------------------------------------------------------------------
// Kernel 3 (TAIL + FINAL): one block per (batch,dir) pair, 1024 threads.
//   A: stream keys into LDS; pass-0 histogram FUSED into this scan (7->6
//      element scans total).
//   B: radix passes 1-3 (pass 0 selection uses the fused histogram).
//   C: fused count(<=key0)/min(>key0) -> linear-interp quantiles.
//   D: two-pass masked mean/std (exact reference arithmetic).
//   E: last-block-done (device counter) computes the final max/mean output
//      -- removes the separate final_kernel launch.
// ---------------------------------------------------------------------------
__global__ __launch_bounds__(TPB_TAIL) void tail_kernel(const unsigned* __restrict__ gkeys,
                                                        float* __restrict__ stats,
                                                        unsigned* __restrict__ done_cnt,
                                                        float* __restrict__ out) {
    __shared__ unsigned keys[NV];           // 48 KB
    __shared__ int hist8[8][256];           // 8 KB
    __shared__ unsigned s_prefix[4];
    __shared__ int s_want[4];
    __shared__ int s_cnt[4];
    __shared__ unsigned s_mn[4];
    __shared__ float s_qv[4];
    __shared__ float red[64];
    __shared__ float sh[8];

    const int pair = blockIdx.x;
    const int tid  = threadIdx.x;
    const int lane = tid & 63;
    const int wid  = tid >> 6;              // 16 waves

    // ---- zero pass-0 histogram BEFORE the fused Phase A atomics ----
    ((int*)hist8)[tid]            = 0;      // 2048 ints, 2 stores/thread
    ((int*)hist8)[tid + TPB_TAIL] = 0;
    if (tid < 4) {
        const float Qs[4] = {0.05f, 0.95f, 0.25f, 0.75f};
        s_prefix[tid] = 0u;
        s_want[tid]   = (int)floorf(Qs[tid] * (float)(NV - 1));
    }
    __syncthreads();

    // ---- Phase A: stream keys into LDS + FUSED pass-0 histogram ----
    const uint4* g4 = (const uint4*)(gkeys + (size_t)pair * NV);
    uint4* l4w = (uint4*)keys;
    int* h0 = hist8[wid & 7];               // wave-group-private copy
    #pragma unroll
    for (int i = 0; i < 3; ++i) {           // NV/4 = 3072 = 3 * 1024 exact
        uint4 kv = g4[i * TPB_TAIL + tid];
        l4w[i * TPB_TAIL + tid] = kv;
        atomicAdd(&h0[kv.x >> 24], 1);
        atomicAdd(&h0[kv.y >> 24], 1);
        atomicAdd(&h0[kv.z >> 24], 1);
        atomicAdd(&h0[kv.w >> 24], 1);
    }
    __syncthreads();

    // ---- Phase B: selection pass 0, then radix passes 1-3 ----
    const uint4* k4 = (const uint4*)keys;
    #pragma unroll 1
    for (int pass = 0; pass < 4; ++pass) {
        const int shift = 24 - 8 * pass;

        if (pass > 0) {
            ((int*)hist8)[tid]            = 0;
            ((int*)hist8)[tid + TPB_TAIL] = 0;
            __syncthreads();
            const unsigned pmask = 0xFFFFFFFFu << (32 - 8 * pass);
            const unsigned pf0 = s_prefix[0], pf1 = s_prefix[1];
            const unsigned pf2 = s_prefix[2], pf3 = s_prefix[3];
            for (int i = tid; i < NV / 4; i += TPB_TAIL) {
                uint4 kv = k4[i];
                const unsigned ks[4] = {kv.x, kv.y, kv.z, kv.w};
                #pragma unroll
                for (int u = 0; u < 4; ++u) {
                    const unsigned k  = ks[u];
                    const unsigned kp = k & pmask;
                    const int bin = (int)((k >> shift) & 255u);
                    if (kp == pf0) atomicAdd(&hist8[0][bin], 1);
                    if (kp == pf1) atomicAdd(&hist8[1][bin], 1);
                    if (kp == pf2) atomicAdd(&hist8[2][bin], 1);
                    if (kp == pf3) atomicAdd(&hist8[3][bin], 1);
                }
            }
            __syncthreads();
        }

        // selection: wave t (t<4) scans quantile t's histogram
        if (wid < 4) {
            int c0 = 0, c1 = 0, c2 = 0, c3 = 0;
            if (pass == 0) {
                #pragma unroll
                for (int cp = 0; cp < 8; ++cp) {
                    c0 += hist8[cp][lane * 4 + 0]; c1 += hist8[cp][lane * 4 + 1];
                    c2 += hist8[cp][lane * 4 + 2]; c3 += hist8[cp][lane * 4 + 3];
                }
            } else {
                c0 = hist8[wid][lane * 4 + 0]; c1 = hist8[wid][lane * 4 + 1];
                c2 = hist8[wid][lane * 4 + 2]; c3 = hist8[wid][lane * 4 + 3];
            }
            const int want = s_want[wid];
            int s = c0 + c1 + c2 + c3;
            int pre = s;
            #pragma unroll
            for (int off = 1; off < 64; off <<= 1) {
                int u = __shfl_up(pre, off);
                if (lane >= off) pre += u;
            }
            const int excl = pre - s;
            const bool hit = (want >= excl) && (want < excl + s);
            unsigned long long m = __ballot(hit);
            const int hl = (int)(__ffsll(m) - 1);
            if (lane == hl) {
                int w = want - excl;
                int sel;
                if      (w < c0)           { sel = lane * 4 + 0; }
                else if (w < c0 + c1)      { sel = lane * 4 + 1; w -= c0; }
                else if (w < c0 + c1 + c2) { sel = lane * 4 + 2; w -= c0 + c1; }
                else                       { sel = lane * 4 + 3; w -= c0 + c1 + c2; }
                s_prefix[wid] |= ((unsigned)sel) << shift;
                s_want[wid] = w;
            }
        }
        __syncthreads();
    }

    // ---- Phase C: count(<=key0) and min(>key0) for all 4 quantiles ----
    if (tid < 4) { s_cnt[tid] = 0; s_mn[tid] = 0xFFFFFFFFu; }
    __syncthreads();
    const unsigned kq0 = s_prefix[0], kq1 = s_prefix[1];
    const unsigned kq2 = s_prefix[2], kq3 = s_prefix[3];
    int cnt0 = 0, cnt1 = 0, cnt2 = 0, cnt3 = 0;
    unsigned mn0 = 0xFFFFFFFFu, mn1 = 0xFFFFFFFFu, mn2 = 0xFFFFFFFFu, mn3 = 0xFFFFFFFFu;
    for (int i = tid; i < NV / 4; i += TPB_TAIL) {
        uint4 kv = k4[i];
        const unsigned ks[4] = {kv.x, kv.y, kv.z, kv.w};
        #pragma unroll
        for (int u = 0; u < 4; ++u) {
            const unsigned k = ks[u];
            if (k <= kq0) cnt0++; else if (k < mn0) mn0 = k;
            if (k <= kq1) cnt1++; else if (k < mn1) mn1 = k;
            if (k <= kq2) cnt2++; else if (k < mn2) mn2 = k;
            if (k <= kq3) cnt3++; else if (k < mn3) mn3 = k;
        }
    }
    #pragma unroll
    for (int off = 32; off > 0; off >>= 1) {
        cnt0 += __shfl_down(cnt0, off); cnt1 += __shfl_down(cnt1, off);
        cnt2 += __shfl_down(cnt2, off); cnt3 += __shfl_down(cnt3, off);
        unsigned u0 = __shfl_down(mn0, off); mn0 = u0 < mn0 ? u0 : mn0;
        unsigned u1 = __shfl_down(mn1, off); mn1 = u1 < mn1 ? u1 : mn1;
        unsigned u2 = __shfl_down(mn2, off); mn2 = u2 < mn2 ? u2 : mn2;
        unsigned u3 = __shfl_down(mn3, off); mn3 = u3 < mn3 ? u3 : mn3;
    }
    if (lane == 0) {
        atomicAdd(&s_cnt[0], cnt0); atomicMin(&s_mn[0], mn0);
        atomicAdd(&s_cnt[1], cnt1); atomicMin(&s_mn[1], mn1);
        atomicAdd(&s_cnt[2], cnt2); atomicMin(&s_mn[2], mn2);
        atomicAdd(&s_cnt[3], cnt3); atomicMin(&s_mn[3], mn3);
    }
    __syncthreads();
    if (tid < 4) {
        const float Qs[4] = {0.05f, 0.95f, 0.25f, 0.75f};
        const float pos = Qs[tid] * (float)(NV - 1);
        const int   k0  = (int)floorf(pos);
        const float fr  = pos - (float)k0;
        const float v0  = k2f(s_prefix[tid]);
        const float v1  = (s_cnt[tid] >= k0 + 2) ? v0 : k2f(s_mn[tid]);
        s_qv[tid] = v0 + fr * (v1 - v0);
    }
    __syncthreads();
    const float q0 = s_qv[0], q1 = s_qv[1], q2 = s_qv[2], q3 = s_qv[3];

    // ---- Phase D: masked two-pass mean/std from LDS keys ----
    float cb = 0.f, sb = 0.f, ce = 0.f, se = 0.f;
    for (int i = tid; i < NV / 4; i += TPB_TAIL) {
        uint4 kv = k4[i];
        const unsigned ks[4] = {kv.x, kv.y, kv.z, kv.w};
        #pragma unroll
        for (int u = 0; u < 4; ++u) {
            const float val = k2f(ks[u]);
            if ((val < q0) || (val > q1)) { cb += 1.f; sb += val; }
            if ((val > q2) && (val < q3)) { ce += 1.f; se += val; }
        }
    }
    #pragma unroll
    for (int off = 32; off > 0; off >>= 1) {
        cb += __shfl_down(cb, off); sb += __shfl_down(sb, off);
        ce += __shfl_down(ce, off); se += __shfl_down(se, off);
    }
    if (lane == 0) {
        red[wid * 4 + 0] = cb; red[wid * 4 + 1] = sb;
        red[wid * 4 + 2] = ce; red[wid * 4 + 3] = se;
    }
    __syncthreads();
    if (tid == 0) {
        float tcb = 0.f, tsb = 0.f, tce = 0.f, tse = 0.f;
        for (int w = 0; w < 16; ++w) {
            tcb += red[w * 4 + 0]; tsb += red[w * 4 + 1];
            tce += red[w * 4 + 2]; tse += red[w * 4 + 3];
        }
        sh[0] = tsb / tcb;  sh[1] = tse / tce;   // means
        sh[2] = tcb;        sh[3] = tce;         // counts
    }
    __syncthreads();
    const float mean_b = sh[0], mean_e = sh[1];
    const float nb = sh[2], ne = sh[3];

    float vb = 0.f, ve = 0.f;
    for (int i = tid; i < NV / 4; i += TPB_TAIL) {
        uint4 kv = k4[i];
        const unsigned ks[4] = {kv.x, kv.y, kv.z, kv.w};
        #pragma unroll
        for (int u = 0; u < 4; ++u) {
            const float val = k2f(ks[u]);
            if ((val < q0) || (val > q1)) { float d = val - mean_b; vb += d * d; }
            if ((val > q2) && (val < q3)) { float d = val - mean_e; ve += d * d; }
        }
    }
    #pragma unroll
    for (int off = 32; off > 0; off >>= 1) {
        vb += __shfl_down(vb, off);
        ve += __shfl_down(ve, off);
    }
    __syncthreads();
    if (lane == 0) { red[wid * 2 + 0] = vb; red[wid * 2 + 1] = ve; }
    __syncthreads();

    // ---- Phase E: write stats; last block computes the final output ----
    if (tid == 0) {
        float tvb = 0.f, tve = 0.f;
        for (int w = 0; w < 16; ++w) { tvb += red[w * 2 + 0]; tve += red[w * 2 + 1]; }
        stats[pair * 2 + 0] = sqrtf(tvb / (nb - 1.f));   // unbiased std, begin
        stats[pair * 2 + 1] = sqrtf(tve / (ne - 1.f));   // unbiased std, end
        __threadfence();                                  // stats visible device-wide
        unsigned prev = atomicAdd(done_cnt, 1u);
        if (prev == 7u) {                                 // this is the 8th block
            volatile float* vs = stats;
            float sbo = 0.f, seo = 0.f;
            for (int b = 0; b < B_; ++b) {
                float b1 = vs[(b * 2 + 0) * 2 + 0];
                float b2 = vs[(b * 2 + 1) * 2 + 0];
                float e1 = vs[(b * 2 + 0) * 2 + 1];
                float e2 = vs[(b * 2 + 1) * 2 + 1];
                sbo += fmaxf(b1, b2);
                seo += fmaxf(e1, e2);
            }
            out[0] = sbo / (float)B_;
            out[1] = seo / (float)B_;
        }
    }
}

extern "C" void kernel_launch(void* const* d_in, const int* in_sizes, int n_in,
                              void* d_out, int out_size, void* d_ws, size_t ws_size,
                              hipStream_t stream) {
    const float* x = (const float*)d_in[0];
    const float* y = (const float*)d_in[1];
    float* out = (float*)d_out;

    // Workspace: [keys 384KB][stats 16f][cnt 4][pad][preX 256KB][preY 256KB][part 4.2MB]
    unsigned* keys  = (unsigned*)d_ws;
    float*    stats = (float*)(keys + (size_t)8 * NV);
    unsigned* dcnt  = (unsigned*)(stats + 16);
    float4*   preX  = (float4*)(stats + 32);            // 16B-aligned
    float4*   preY  = preX + (size_t)B_ * N_;
    float2*   part  = (float2*)(preY + (size_t)B_ * N_);

    prescale_kernel<<<dim3(B_ * N_ / 256, 2), 256, 0, stream>>>(x, y, preX, preY, dcnt);
    nn_scalar_kernel<<<dim3(NCCH, N_ / 256, 8), 256, 0, stream>>>(x, y, preX, preY, part);
    merge_keys_kernel<<<dim3(N_ / 256, 8), 256, 0, stream>>>(x, y, part, keys);
    tail_kernel<<<8, TPB_TAIL, 0, stream>>>(keys, stats, dcnt, out);
}

// Round 21
// 65.673 us; speedup vs baseline: 1.8817x; 1.0003x over previous
//
#include <hip/hip_runtime.h>
#include <math.h>

// Problem constants (fixed by the reference: B=4, N=4096, D=3)
constexpr int B_  = 4;
constexpr int N_  = 4096;
constexpr int NV  = N_ * 3;      // 12288 flattened residual elements per (batch,dir)
constexpr int NCCH = 16;         // candidate chunks (R13-proven config)
constexpr int CCH  = N_ / NCCH;  // 256 candidates per chunk
constexpr int TPB_TAIL = 1024;   // tail kernel block size

// float <-> monotonic uint key (order-preserving bijection on finite floats)
__device__ inline unsigned f2k(float f) {
    unsigned b = __float_as_uint(f);
    return b ^ ((unsigned)((int)b >> 31) | 0x80000000u);
}
__device__ inline float k2f(unsigned k) {
    unsigned b = (k & 0x80000000u) ? (k ^ 0x80000000u) : ~k;
    return __uint_as_float(b);
}

// ---------------------------------------------------------------------------
// Kernel 0: precompute candidates: pre[t] = {bx,by,bz,|b|^2} (UNSCALED --
// so the NN inner loop's d2 = fmaf(-2.0, dot, c.w) uses the free inline
// constant -2.0 and at most ONE SGPR operand per VALU instruction; the old
// prescaled form fmaf(az,c.z,c.w) read 2 SGPRs -> hidden v_mov/candidate).
// Also zeroes the tail completion counter.
// ---------------------------------------------------------------------------
__global__ __launch_bounds__(256) void prescale_kernel(const float* __restrict__ x,
                                                       const float* __restrict__ y,
                                                       float4* __restrict__ preX,
                                                       float4* __restrict__ preY,
                                                       unsigned* __restrict__ done_cnt) {
    if (blockIdx.x == 0 && blockIdx.y == 0 && threadIdx.x == 0) *done_cnt = 0u;
    const int t = blockIdx.x * 256 + threadIdx.x;        // 0 .. B_*N_-1
    const float* src = blockIdx.y == 0 ? x : y;
    float4* dst      = blockIdx.y == 0 ? preX : preY;
    float bx = src[t * 3 + 0];
    float by = src[t * 3 + 1];
    float bz = src[t * 3 + 2];
    dst[t] = make_float4(bx, by, bz, bx * bx + by * by + bz * bz);
}

// ---------------------------------------------------------------------------
// Kernel 1: partial NN, scalar candidate loads, QPT=1 (R13 config: 26.3us
// measured via R14 double-launch; QPT=2/4/8 variants all regressed).
// grid = (NCCH=16, N/256 qchunks, 8 pairs) = 2048 blocks = 8 blocks/CU.
// Inner loop per candidate: v_mul + 2x v_fma (dot, 1 SGPR each) +
// v_fma(-2.0 inline, dot, c.w: 1 SGPR) + v_cmp + v_cndmask + v_min = 7 VALU,
// zero movs (gfx950 allows max 1 SGPR read per VALU instruction).
// d2 = |b|^2 - 2 a.b ; same formula/rounding as R2 (passed absmax 0.0).
// Strict '<' keeps the FIRST minimal index (jnp.argmin tie-break).
// ---------------------------------------------------------------------------
__global__ __launch_bounds__(256) void nn_scalar_kernel(const float* __restrict__ x,
                                                        const float* __restrict__ y,
                                                        const float4* __restrict__ preX,
                                                        const float4* __restrict__ preY,
                                                        float2* __restrict__ part) {
    const int pair = blockIdx.z;
    const int b    = pair >> 1;
    const int dir  = pair & 1;              // 0: S1=x,S2=y ; 1: S1=y,S2=x
    const float*  S1 = (dir == 0 ? x : y) + b * NV;
    const float4* P2 = (dir == 0 ? preY : preX) + b * N_;
    const int cbase = blockIdx.x * CCH;

    const int q = blockIdx.y * 256 + threadIdx.x;
    const float ax = S1[q * 3 + 0];
    const float ay = S1[q * 3 + 1];
    const float az = S1[q * 3 + 2];

    float bd = INFINITY;
    int idx = 0;
    #pragma unroll 16
    for (int j = 0; j < CCH; ++j) {
        const float4 c = P2[cbase + j];     // wave-uniform -> scalar load
        float dot = fmaf(az, c.z, fmaf(ay, c.y, ax * c.x));
        float d2  = fmaf(-2.0f, dot, c.w);  // inline -2.0; c.w single SGPR
        if (d2 < bd) idx = cbase + j;       // v_cmp + v_cndmask
        bd = fminf(d2, bd);                 // v_min
    }
    part[(size_t)(pair * NCCH + blockIdx.x) * N_ + q] = make_float2(bd, (float)idx);
}

// ---------------------------------------------------------------------------
// Kernel 2: parallel merge. grid = (N_/256, 8 pairs), block = 256 (WIDE --
// R8/R15 both proved the merge must NOT live in the 8-block tail).
// NCCH fully unrolled -> independent dwordx2 loads, ascending chunk order +
// strict '<' == global first-index argmin.  Writes monotonic keys
// component-major (keys[pair][comp*N+q]) -- fully coalesced.
// ---------------------------------------------------------------------------
__global__ __launch_bounds__(256) void merge_keys_kernel(const float* __restrict__ x,
                                                         const float* __restrict__ y,
                                                         const float2* __restrict__ part,
                                                         unsigned* __restrict__ keys) {
    const int pair = blockIdx.y;
    const int b    = pair >> 1;
    const int dir  = pair & 1;
    const float* S1 = (dir == 0 ? x : y) + b * NV;
    const float* S2 = (dir == 0 ? y : x) + b * NV;
    const int q = blockIdx.x * 256 + threadIdx.x;

    float best = INFINITY;
    int bidx = 0;
    #pragma unroll
    for (int c = 0; c < NCCH; ++c) {
        float2 p = part[(size_t)(pair * NCCH + c) * N_ + q];
        if (p.x < best) { best = p.x; bidx = (int)p.y; }
    }
    unsigned* kp = keys + (size_t)pair * NV;
    kp[0 * N_ + q] = f2k(S1[q * 3 + 0] - S2[bidx * 3 + 0]);
    kp[1 * N_ + q] = f2k(S1[q * 3 + 1] - S2[bidx * 3 + 1]);
    kp[2 * N_ + q] = f2k(S1[q * 3 + 2] - S2[bidx * 3 + 2]);
}

// ---------------------------------------------------------------------------
// Kernel 3 (TAIL + FINAL): one block per (batch,dir) pair, 1024 threads.
//   A: stream keys into LDS; pass-0 histogram fused into this scan.
//   B: radix passes 1-3 (pass 0 selection uses the fused histogram).
//   C: fused count(<=key0)/min(>key0) -> linear-interp quantiles.
//   D: two-pass masked mean/std (exact reference arithmetic).
//   E: last-block-done computes the final max/mean output.
// ---------------------------------------------------------------------------
__global__ __launch_bounds__(TPB_TAIL) void tail_kernel(const unsigned* __restrict__ gkeys,
                                                        float* __restrict__ stats,
                                                        unsigned* __restrict__ done_cnt,
                                                        float* __restrict__ out) {
    __shared__ unsigned keys[NV];           // 48 KB
    __shared__ int hist8[8][256];           // 8 KB
    __shared__ unsigned s_prefix[4];
    __shared__ int s_want[4];
    __shared__ int s_cnt[4];
    __shared__ unsigned s_mn[4];
    __shared__ float s_qv[4];
    __shared__ float red[64];
    __shared__ float sh[8];

    const int pair = blockIdx.x;
    const int tid  = threadIdx.x;
    const int lane = tid & 63;
    const int wid  = tid >> 6;              // 16 waves

    // ---- zero pass-0 histogram BEFORE the fused Phase A atomics ----
    ((int*)hist8)[tid]            = 0;      // 2048 ints, 2 stores/thread
    ((int*)hist8)[tid + TPB_TAIL] = 0;
    if (tid < 4) {
        const float Qs[4] = {0.05f, 0.95f, 0.25f, 0.75f};
        s_prefix[tid] = 0u;
        s_want[tid]   = (int)floorf(Qs[tid] * (float)(NV - 1));
    }
    __syncthreads();

    // ---- Phase A: stream keys into LDS + FUSED pass-0 histogram ----
    const uint4* g4 = (const uint4*)(gkeys + (size_t)pair * NV);
    uint4* l4w = (uint4*)keys;
    int* h0 = hist8[wid & 7];               // wave-group-private copy
    #pragma unroll
    for (int i = 0; i < 3; ++i) {           // NV/4 = 3072 = 3 * 1024 exact
        uint4 kv = g4[i * TPB_TAIL + tid];
        l4w[i * TPB_TAIL + tid] = kv;
        atomicAdd(&h0[kv.x >> 24], 1);
        atomicAdd(&h0[kv.y >> 24], 1);
        atomicAdd(&h0[kv.z >> 24], 1);
        atomicAdd(&h0[kv.w >> 24], 1);
    }
    __syncthreads();

    // ---- Phase B: selection pass 0, then radix passes 1-3 ----
    const uint4* k4 = (const uint4*)keys;
    #pragma unroll 1
    for (int pass = 0; pass < 4; ++pass) {
        const int shift = 24 - 8 * pass;

        if (pass > 0) {
            ((int*)hist8)[tid]            = 0;
            ((int*)hist8)[tid + TPB_TAIL] = 0;
            __syncthreads();
            const unsigned pmask = 0xFFFFFFFFu << (32 - 8 * pass);
            const unsigned pf0 = s_prefix[0], pf1 = s_prefix[1];
            const unsigned pf2 = s_prefix[2], pf3 = s_prefix[3];
            for (int i = tid; i < NV / 4; i += TPB_TAIL) {
                uint4 kv = k4[i];
                const unsigned ks[4] = {kv.x, kv.y, kv.z, kv.w};
                #pragma unroll
                for (int u = 0; u < 4; ++u) {
                    const unsigned k  = ks[u];
                    const unsigned kp = k & pmask;
                    const int bin = (int)((k >> shift) & 255u);
                    if (kp == pf0) atomicAdd(&hist8[0][bin], 1);
                    if (kp == pf1) atomicAdd(&hist8[1][bin], 1);
                    if (kp == pf2) atomicAdd(&hist8[2][bin], 1);
                    if (kp == pf3) atomicAdd(&hist8[3][bin], 1);
                }
            }
            __syncthreads();
        }

        // selection: wave t (t<4) scans quantile t's histogram
        if (wid < 4) {
            int c0 = 0, c1 = 0, c2 = 0, c3 = 0;
            if (pass == 0) {
                #pragma unroll
                for (int cp = 0; cp < 8; ++cp) {
                    c0 += hist8[cp][lane * 4 + 0]; c1 += hist8[cp][lane * 4 + 1];
                    c2 += hist8[cp][lane * 4 + 2]; c3 += hist8[cp][lane * 4 + 3];
                }
            } else {
                c0 = hist8[wid][lane * 4 + 0]; c1 = hist8[wid][lane * 4 + 1];
                c2 = hist8[wid][lane * 4 + 2]; c3 = hist8[wid][lane * 4 + 3];
            }
            const int want = s_want[wid];
            int s = c0 + c1 + c2 + c3;
            int pre = s;
            #pragma unroll
            for (int off = 1; off < 64; off <<= 1) {
                int u = __shfl_up(pre, off);
                if (lane >= off) pre += u;
            }
            const int excl = pre - s;
            const bool hit = (want >= excl) && (want < excl + s);
            unsigned long long m = __ballot(hit);
            const int hl = (int)(__ffsll(m) - 1);
            if (lane == hl) {
                int w = want - excl;
                int sel;
                if      (w < c0)           { sel = lane * 4 + 0; }
                else if (w < c0 + c1)      { sel = lane * 4 + 1; w -= c0; }
                else if (w < c0 + c1 + c2) { sel = lane * 4 + 2; w -= c0 + c1; }
                else                       { sel = lane * 4 + 3; w -= c0 + c1 + c2; }
                s_prefix[wid] |= ((unsigned)sel) << shift;
                s_want[wid] = w;
            }
        }
        __syncthreads();
    }

    // ---- Phase C: count(<=key0) and min(>key0) for all 4 quantiles ----
    if (tid < 4) { s_cnt[tid] = 0; s_mn[tid] = 0xFFFFFFFFu; }
    __syncthreads();
    const unsigned kq0 = s_prefix[0], kq1 = s_prefix[1];
    const unsigned kq2 = s_prefix[2], kq3 = s_prefix[3];
    int cnt0 = 0, cnt1 = 0, cnt2 = 0, cnt3 = 0;
    unsigned mn0 = 0xFFFFFFFFu, mn1 = 0xFFFFFFFFu, mn2 = 0xFFFFFFFFu, mn3 = 0xFFFFFFFFu;
    for (int i = tid; i < NV / 4; i += TPB_TAIL) {
        uint4 kv = k4[i];
        const unsigned ks[4] = {kv.x, kv.y, kv.z, kv.w};
        #pragma unroll
        for (int u = 0; u < 4; ++u) {
            const unsigned k = ks[u];
            if (k <= kq0) cnt0++; else if (k < mn0) mn0 = k;
            if (k <= kq1) cnt1++; else if (k < mn1) mn1 = k;
            if (k <= kq2) cnt2++; else if (k < mn2) mn2 = k;
            if (k <= kq3) cnt3++; else if (k < mn3) mn3 = k;
        }
    }
    #pragma unroll
    for (int off = 32; off > 0; off >>= 1) {
        cnt0 += __shfl_down(cnt0, off); cnt1 += __shfl_down(cnt1, off);
        cnt2 += __shfl_down(cnt2, off); cnt3 += __shfl_down(cnt3, off);
        unsigned u0 = __shfl_down(mn0, off); mn0 = u0 < mn0 ? u0 : mn0;
        unsigned u1 = __shfl_down(mn1, off); mn1 = u1 < mn1 ? u1 : mn1;
        unsigned u2 = __shfl_down(mn2, off); mn2 = u2 < mn2 ? u2 : mn2;
        unsigned u3 = __shfl_down(mn3, off); mn3 = u3 < mn3 ? u3 : mn3;
    }
    if (lane == 0) {
        atomicAdd(&s_cnt[0], cnt0); atomicMin(&s_mn[0], mn0);
        atomicAdd(&s_cnt[1], cnt1); atomicMin(&s_mn[1], mn1);
        atomicAdd(&s_cnt[2], cnt2); atomicMin(&s_mn[2], mn2);
        atomicAdd(&s_cnt[3], cnt3); atomicMin(&s_mn[3], mn3);
    }
    __syncthreads();
    if (tid < 4) {
        const float Qs[4] = {0.05f, 0.95f, 0.25f, 0.75f};
        const float pos = Qs[tid] * (float)(NV - 1);
        const int   k0  = (int)floorf(pos);
        const float fr  = pos - (float)k0;
        const float v0  = k2f(s_prefix[tid]);
        const float v1  = (s_cnt[tid] >= k0 + 2) ? v0 : k2f(s_mn[tid]);
        s_qv[tid] = v0 + fr * (v1 - v0);
    }
    __syncthreads();
    const float q0 = s_qv[0], q1 = s_qv[1], q2 = s_qv[2], q3 = s_qv[3];

    // ---- Phase D: masked two-pass mean/std from LDS keys ----
    float cb = 0.f, sb = 0.f, ce = 0.f, se = 0.f;
    for (int i = tid; i < NV / 4; i += TPB_TAIL) {
        uint4 kv = k4[i];
        const unsigned ks[4] = {kv.x, kv.y, kv.z, kv.w};
        #pragma unroll
        for (int u = 0; u < 4; ++u) {
            const float val = k2f(ks[u]);
            if ((val < q0) || (val > q1)) { cb += 1.f; sb += val; }
            if ((val > q2) && (val < q3)) { ce += 1.f; se += val; }
        }
    }
    #pragma unroll
    for (int off = 32; off > 0; off >>= 1) {
        cb += __shfl_down(cb, off); sb += __shfl_down(sb, off);
        ce += __shfl_down(ce, off); se += __shfl_down(se, off);
    }
    if (lane == 0) {
        red[wid * 4 + 0] = cb; red[wid * 4 + 1] = sb;
        red[wid * 4 + 2] = ce; red[wid * 4 + 3] = se;
    }
    __syncthreads();
    if (tid == 0) {
        float tcb = 0.f, tsb = 0.f, tce = 0.f, tse = 0.f;
        for (int w = 0; w < 16; ++w) {
            tcb += red[w * 4 + 0]; tsb += red[w * 4 + 1];
            tce += red[w * 4 + 2]; tse += red[w * 4 + 3];
        }
        sh[0] = tsb / tcb;  sh[1] = tse / tce;   // means
        sh[2] = tcb;        sh[3] = tce;         // counts
    }
    __syncthreads();
    const float mean_b = sh[0], mean_e = sh[1];
    const float nb = sh[2], ne = sh[3];

    float vb = 0.f, ve = 0.f;
    for (int i = tid; i < NV / 4; i += TPB_TAIL) {
        uint4 kv = k4[i];
        const unsigned ks[4] = {kv.x, kv.y, kv.z, kv.w};
        #pragma unroll
        for (int u = 0; u < 4; ++u) {
            const float val = k2f(ks[u]);
            if ((val < q0) || (val > q1)) { float d = val - mean_b; vb += d * d; }
            if ((val > q2) && (val < q3)) { float d = val - mean_e; ve += d * d; }
        }
    }
    #pragma unroll
    for (int off = 32; off > 0; off >>= 1) {
        vb += __shfl_down(vb, off);
        ve += __shfl_down(ve, off);
    }
    __syncthreads();
    if (lane == 0) { red[wid * 2 + 0] = vb; red[wid * 2 + 1] = ve; }
    __syncthreads();

    // ---- Phase E: write stats; last block computes the final output ----
    if (tid == 0) {
        float tvb = 0.f, tve = 0.f;
        for (int w = 0; w < 16; ++w) { tvb += red[w * 2 + 0]; tve += red[w * 2 + 1]; }
        stats[pair * 2 + 0] = sqrtf(tvb / (nb - 1.f));   // unbiased std, begin
        stats[pair * 2 + 1] = sqrtf(tve / (ne - 1.f));   // unbiased std, end
        __threadfence();                                  // stats visible device-wide
        unsigned prev = atomicAdd(done_cnt, 1u);
        if (prev == 7u) {                                 // this is the 8th block
            volatile float* vs = stats;
            float sbo = 0.f, seo = 0.f;
            for (int b = 0; b < B_; ++b) {
                float b1 = vs[(b * 2 + 0) * 2 + 0];
                float b2 = vs[(b * 2 + 1) * 2 + 0];
                float e1 = vs[(b * 2 + 0) * 2 + 1];
                float e2 = vs[(b * 2 + 1) * 2 + 1];
                sbo += fmaxf(b1, b2);
                seo += fmaxf(e1, e2);
            }
            out[0] = sbo / (float)B_;
            out[1] = seo / (float)B_;
        }
    }
}

extern "C" void kernel_launch(void* const* d_in, const int* in_sizes, int n_in,
                              void* d_out, int out_size, void* d_ws, size_t ws_size,
                              hipStream_t stream) {
    const float* x = (const float*)d_in[0];
    const float* y = (const float*)d_in[1];
    float* out = (float*)d_out;

    // Workspace: [keys 384KB][stats 16f][cnt 4][pad][preX 256KB][preY 256KB][part 4.2MB]
    unsigned* keys  = (unsigned*)d_ws;
    float*    stats = (float*)(keys + (size_t)8 * NV);
    unsigned* dcnt  = (unsigned*)(stats + 16);
    float4*   preX  = (float4*)(stats + 32);            // 16B-aligned
    float4*   preY  = preX + (size_t)B_ * N_;
    float2*   part  = (float2*)(preY + (size_t)B_ * N_);

    prescale_kernel<<<dim3(B_ * N_ / 256, 2), 256, 0, stream>>>(x, y, preX, preY, dcnt);
    nn_scalar_kernel<<<dim3(NCCH, N_ / 256, 8), 256, 0, stream>>>(x, y, preX, preY, part);
    merge_keys_kernel<<<dim3(N_ / 256, 8), 256, 0, stream>>>(x, y, part, keys);
    tail_kernel<<<8, TPB_TAIL, 0, stream>>>(keys, stats, dcnt, out);
}